// Round 12
// baseline (965.012 us; speedup 1.0000x reference)
//
#include <hip/hip_runtime.h>
#include <math.h>

#define NB 8
#define NP 4096
#define FEAT_SZ (NB * NP * 128)
#define INVBN 0.9999950000374999f  // 1/sqrt(1+1e-5), f32-rounded
#define SPLIT 2
#define CHUNKS 32                  // 4096 cols / 64 / SPLIT

typedef unsigned long long u64;
typedef unsigned int u32;

// monotone map: float -> u32 preserving order (larger float -> larger u32)
__device__ __forceinline__ u32 fmap(float f) {
    u32 b = __float_as_uint(f);
    return b ^ ((u32)((int)b >> 31) | 0x80000000u);
}

__device__ __forceinline__ u64 umax64(u64 a, u64 b) { return a > b ? a : b; }

// insert key into descending-sorted v[16] if it beats the current 16th.
__device__ __forceinline__ void kins(u64 (&v)[16], u64 key) {
    if (key <= v[15]) return;
    bool bb[16];
#pragma unroll
    for (int j = 0; j < 16; ++j) bb[j] = key > v[j];
#pragma unroll
    for (int j = 15; j >= 1; --j) v[j] = bb[j] ? (bb[j - 1] ? v[j - 1] : key) : v[j];
    if (bb[0]) v[0] = key;
}

__device__ __forceinline__ void bufpush(u64 (&v)[16], u64 &q0, u64 &q1, u64 &q2, u64 &q3,
                                        int &cnt, u64 key) {
    if (cnt < 4) {
        q0 = cnt == 0 ? key : q0;
        q1 = cnt == 1 ? key : q1;
        q2 = cnt == 2 ? key : q2;
        q3 = cnt == 3 ? key : q3;
        ++cnt;
    } else {
        kins(v, key);   // rare overflow fallback (exactness guarantee)
    }
}

__device__ __forceinline__ void bufflush(u64 (&v)[16], u64 &q0, u64 &q1, u64 &q2, u64 &q3,
                                         int &cnt) {
    kins(v, q0); kins(v, q1); kins(v, q2); kins(v, q3);
    q0 = 0; q1 = 0; q2 = 0; q3 = 0; cnt = 0;
}

// bitonic clean (desc) of a bitonic 16-sequence -> fully sorted desc
__device__ __forceinline__ void bclean(u64 (&v)[16]) {
#pragma unroll
    for (int d = 8; d; d >>= 1) {
#pragma unroll
        for (int i = 0; i < 16; ++i) {
            if ((i & d) == 0) {
                u64 a = v[i], b = v[i | d];
                bool s = a < b;
                v[i] = s ? b : a;
                v[i | d] = s ? a : b;
            }
        }
    }
}

__device__ __forceinline__ void merge_shfl(u64 (&v)[16], int off) {
    u64 o[16];
#pragma unroll
    for (int j = 0; j < 16; ++j) o[j] = __shfl_down(v[j], off);
#pragma unroll
    for (int j = 0; j < 16; ++j) {
        u64 b = o[15 - j];
        v[j] = v[j] > b ? v[j] : b;
    }
    bclean(v);
}

__device__ __forceinline__ u64 rowmax16(u64 x) {
    x = umax64(x, __shfl_xor(x, 1));
    x = umax64(x, __shfl_xor(x, 2));
    x = umax64(x, __shfl_xor(x, 4));
    x = umax64(x, __shfl_xor(x, 8));
    return x;
}

// ------- kernel A: point-space kNN (k=16) + fused edge-conv1_1/1_2 -------
// 32 rows/block. Selection: 2 rows/thread, 16 threads/row (one pts[m] read
// serves 2 rows). Then edge12 computed in-block: neighbor positions via
// LDS broadcast from pts[], indices via midx. f12 bitwise == old pipeline.
__global__ __launch_bounds__(256) void knn_point_edge12_kernel(
    const float* __restrict__ point,
    const float* __restrict__ w11, const float* __restrict__ b11,
    const float* __restrict__ g11, const float* __restrict__ bb11,
    const float* __restrict__ w12, const float* __restrict__ b12,
    const float* __restrict__ g12, const float* __restrict__ bb12,
    float* __restrict__ f12) {
    __shared__ float4 pts[NP];    // (x,y,z,xx) 64KB
    __shared__ int midx[32][16];  // 2KB
    int bt = blockIdx.x >> 7;
    int n0 = (blockIdx.x & 127) << 5;
    const float* pb = point + (size_t)bt * 3 * NP;
    for (int m = threadIdx.x; m < NP; m += 256) {
        float x = pb[m], y = pb[NP + m], z = pb[2 * NP + m];
        pts[m] = make_float4(x, y, z, fmaf(z, z, fmaf(y, y, x * x)));
    }
    __syncthreads();
    int t = threadIdx.x;
    int q = t & 15;               // m-partition (16 threads per row-pair)
    int rq = t >> 4;              // row-pair 0..15
    float4 c0 = pts[n0 + rq * 2];
    float4 c1 = pts[n0 + rq * 2 + 1];
    u64 v0[16], v1[16];
#pragma unroll
    for (int j = 0; j < 16; ++j) { v0[j] = 0; v1[j] = 0; }
    u64 A0 = 0, A1 = 0, A2 = 0, A3 = 0;
    u64 B0 = 0, B1 = 0, B2 = 0, B3 = 0;
    int cA = 0, cB = 0;
    u64 th0 = 0, th1 = 0;
#pragma unroll 1
    for (int o = 0; o < 8; ++o) {
#pragma unroll 4
        for (int ii = 0; ii < 32; ++ii) {
            int m = (((o << 5) + ii) << 4) + q;   // ascending per thread
            float4 p = pts[m];                    // shared by both rows
            float in0 = fmaf(c0.z, p.z, fmaf(c0.y, p.y, c0.x * p.x));
            float pd0 = fmaf(2.0f, in0, -c0.w) - p.w;
            u64 k0 = ((u64)fmap(pd0) << 32) | (u64)(u32)~m;
            if (k0 > th0) bufpush(v0, A0, A1, A2, A3, cA, k0);
            float in1 = fmaf(c1.z, p.z, fmaf(c1.y, p.y, c1.x * p.x));
            float pd1 = fmaf(2.0f, in1, -c1.w) - p.w;
            u64 k1 = ((u64)fmap(pd1) << 32) | (u64)(u32)~m;
            if (k1 > th1) bufpush(v1, B0, B1, B2, B3, cB, k1);
        }
        if (__any((cA >= 3) || (cB >= 3))) {
            bufflush(v0, A0, A1, A2, A3, cA);
            bufflush(v1, B0, B1, B2, B3, cB);
            th0 = rowmax16(v0[15]);
            th1 = rowmax16(v1[15]);
        }
    }
    bufflush(v0, A0, A1, A2, A3, cA);
    bufflush(v1, B0, B1, B2, B3, cB);
    merge_shfl(v0, 8); merge_shfl(v0, 4); merge_shfl(v0, 2); merge_shfl(v0, 1);
    merge_shfl(v1, 8); merge_shfl(v1, 4); merge_shfl(v1, 2); merge_shfl(v1, 1);
    if (q == 0) {
#pragma unroll
        for (int j = 0; j < 16; ++j) {
            midx[rq * 2][j] = (int)~(u32)v0[j];
            midx[rq * 2 + 1][j] = (int)~(u32)v1[j];
        }
    }
    __syncthreads();
    // ---- edge12 phase: wave w handles points w*8..+7; lane = channel ----
    int lane = t & 63, w = t >> 6;
    float wd1[3], wc1[3], wd2[3], wc2[3];
#pragma unroll
    for (int c = 0; c < 3; ++c) {
        wd1[c] = w11[c * 64 + lane]; wc1[c] = w11[(3 + c) * 64 + lane];
        wd2[c] = w12[c * 64 + lane]; wc2[c] = w12[(3 + c) * 64 + lane];
    }
    float s1 = g11[lane] * INVBN, sh1 = bb11[lane];
    float s2 = g12[lane] * INVBN, sh2 = bb12[lane];
#pragma unroll 1
    for (int pp = 0; pp < 8; ++pp) {
        int pl = w * 8 + pp;
        size_t pt = (size_t)bt * NP + n0 + pl;
        float4 cc = pts[n0 + pl];            // uniform -> LDS broadcast
        float base1 = fmaf(wc1[2], cc.z, fmaf(wc1[1], cc.y, fmaf(wc1[0], cc.x, b11[lane])));
        float base2 = fmaf(wc2[2], cc.z, fmaf(wc2[1], cc.y, fmaf(wc2[0], cc.x, b12[lane])));
        float a1 = -INFINITY, a2 = -INFINITY;
#pragma unroll
        for (int j = 0; j < 16; ++j) {
            int m = midx[pl][j];
            float4 pm = pts[m];              // uniform -> LDS broadcast
            float ex = pm.x - cc.x, ey = pm.y - cc.y, ez = pm.z - cc.z;
            float y2 = fmaf(wd2[2], ez, fmaf(wd2[1], ey, fmaf(wd2[0], ex, base2)));
            float z2 = fmaf(y2, s2, sh2);
            z2 = z2 >= 0.f ? z2 : 0.2f * z2;
            a2 = fmaxf(a2, z2);
            if (j < 8) {  // top-8 is prefix of sorted top-16
                float y1 = fmaf(wd1[2], ez, fmaf(wd1[1], ey, fmaf(wd1[0], ex, base1)));
                float z1 = fmaf(y1, s1, sh1);
                z1 = z1 >= 0.f ? z1 : 0.2f * z1;
                a1 = fmaxf(a1, z1);
            }
        }
        f12[(pt << 7) + lane] = a1;
        f12[(pt << 7) + 64 + lane] = a2;
    }
}

// ---------------- generic register-tiled GEMM + activation ----------------
template<int K, int O, int MODE, bool XX>
__global__ __launch_bounds__(256) void gemm_act_kernel(
        const float* __restrict__ in, const float* __restrict__ W,
        const float* __restrict__ b, const float* __restrict__ g,
        const float* __restrict__ s, float* __restrict__ outp,
        float* __restrict__ xxo) {
    __shared__ __align__(16) char smem[64 * (K + 1) * 4 + K * O * 4];
    float* A  = (float*)smem;
    float* Wl = (float*)(smem + 64 * (K + 1) * 4);
    float* Hs = (float*)smem;   // [64][65] alias over A (used only when XX, after barrier)
    constexpr int F4R = K / 4;
#pragma unroll
    for (int i = 0; i < 64 * F4R / 256; ++i) {
        int f = threadIdx.x + i * 256;
        int pt = f / F4R, c4 = f % F4R;
        float4 v = *(const float4*)(in + ((size_t)blockIdx.x * 64 + pt) * K + c4 * 4);
        float* d = A + pt * (K + 1) + c4 * 4;
        d[0] = v.x; d[1] = v.y; d[2] = v.z; d[3] = v.w;
    }
    if constexpr (MODE == 0) {
#pragma unroll
        for (int i = 0; i < 8; ++i) {
            int f = threadIdx.x + i * 256;
            int half = f >= 1024;
            int fr = f & 1023;
            int c = fr >> 4, o4 = fr & 15;
            const float* src = half ? (W + (64 + c) * 64 + o4 * 4) : (W + c * 64 + o4 * 4);
            float4 v = *(const float4*)src;
            float* d = Wl + c * 128 + half * 64 + o4 * 4;
            d[0] = v.x; d[1] = v.y; d[2] = v.z; d[3] = v.w;
        }
    } else {
#pragma unroll
        for (int i = 0; i < K * O / 1024; ++i) {
            int f = threadIdx.x + i * 256;
            *(float4*)(Wl + f * 4) = *(const float4*)(W + f * 4);
        }
    }
    __syncthreads();
    constexpr int NO = O / 8;
    int po = threadIdx.x & 7, pp = threadIdx.x >> 3;
    int pt0 = pp * 2, o0 = po * NO;
    float acc[2][NO];
#pragma unroll
    for (int i = 0; i < NO; ++i) {
        int o = o0 + i;
        float init;
        if constexpr (MODE == 0) init = (o < 64) ? 0.f : b[o - 64];
        else init = b[o];
        acc[0][i] = init;
        acc[1][i] = init;
    }
#pragma unroll 8
    for (int kk = 0; kk < K; ++kk) {
        float a0 = A[pt0 * (K + 1) + kk];
        float a1 = A[(pt0 + 1) * (K + 1) + kk];
        float w[NO];
#pragma unroll
        for (int i4 = 0; i4 < NO / 4; ++i4) {
            float4 wv = *(const float4*)(Wl + kk * O + o0 + i4 * 4);
            w[i4 * 4 + 0] = wv.x; w[i4 * 4 + 1] = wv.y;
            w[i4 * 4 + 2] = wv.z; w[i4 * 4 + 3] = wv.w;
        }
#pragma unroll
        for (int i = 0; i < NO; ++i) {
            acc[0][i] = fmaf(a0, w[i], acc[0][i]);   // ascending-k chain
            acc[1][i] = fmaf(a1, w[i], acc[1][i]);
        }
    }
    float tact[2][NO];
#pragma unroll
    for (int p = 0; p < 2; ++p) {
#pragma unroll
        for (int i = 0; i < NO; ++i) {
            int o = o0 + i;
            float a = acc[p][i];
            if constexpr (MODE == 0) {
                tact[p][i] = a;
            } else {
                float vv = fmaf(a, g[o] * INVBN, s[o]);
                tact[p][i] = vv >= 0.f ? vv : 0.2f * vv;
            }
        }
    }
#pragma unroll
    for (int p = 0; p < 2; ++p) {
        size_t rowg = (size_t)blockIdx.x * 64 + pt0 + p;
#pragma unroll
        for (int i4 = 0; i4 < NO / 4; ++i4) {
            float4 ov;
            ov.x = tact[p][i4 * 4 + 0]; ov.y = tact[p][i4 * 4 + 1];
            ov.z = tact[p][i4 * 4 + 2]; ov.w = tact[p][i4 * 4 + 3];
            *(float4*)(outp + rowg * O + o0 + i4 * 4) = ov;
        }
    }
    if constexpr (XX) {
        __syncthreads();   // all A reads done; Hs may alias A now
#pragma unroll
        for (int p = 0; p < 2; ++p)
#pragma unroll
            for (int i = 0; i < NO; ++i)
                Hs[(pt0 + p) * 65 + o0 + i] = tact[p][i];
        __syncthreads();
        if (threadIdx.x < 64) {
            float ss = 0.f;
#pragma unroll
            for (int c = 0; c < 64; ++c) {
                float hc = Hs[threadIdx.x * 65 + c];
                ss = fmaf(hc, hc, ss);   // ascending-c chain == old xxf chain
            }
            xxo[(size_t)blockIdx.x * 64 + threadIdx.x] = ss;
        }
    }
}

// ---------------- kernel C: feature-space kNN (C=64, k=16) ----------------
// 128 rows x 64 cols/chunk, 80KB LDS (proven-best structure).
__global__ __launch_bounds__(256, 2) void knn_feat_kernel(const float* __restrict__ h1t,
                                                          const float* __restrict__ xxf,
                                                          u64* __restrict__ partF) {
    __shared__ __align__(16) char smem[81920];
    float* At = (float*)smem;                  // [64ch][128row swizzled] 32KB
    float* Bt = (float*)(smem + 32768);        // [64ch][64col swizzled]  16KB
    u32*   Sb = (u32*)(smem + 49152);          // [128row][64col swizzled] 32KB
    int seg = blockIdx.x & 1;
    int rg  = (blockIdx.x >> 1) & 31;
    int bt  = blockIdx.x >> 6;
    int n0  = rg << 7;
    int tid = threadIdx.x;
    int rp = tid >> 4;
    int cg = tid & 15;
    int cs = cg << 2;
    const float* hbase = h1t + ((size_t)bt * NP << 6);
    const float* hA = hbase + ((size_t)n0 << 6);
#pragma unroll
    for (int rep = 0; rep < 8; ++rep) {
        int row = rep * 16 + rp;
        float4 va = *(const float4*)(hA + (row << 6) + cs);
        float fv[4] = {va.x, va.y, va.z, va.w};
#pragma unroll
        for (int i = 0; i < 4; ++i) {
            int ch = cs + i;
            int rw = row ^ ((row & 32) >> 3) ^ (((ch >> 2) & 7) << 2);
            At[ch * 128 + rw] = fv[i];
        }
    }
    int m00 = seg * (CHUNKS * 64);
#pragma unroll
    for (int rep = 0; rep < 4; ++rep) {
        int col = rep * 16 + rp;
        float4 vb = *(const float4*)(hbase + ((size_t)(m00 + col) << 6) + cs);
        float fv[4] = {vb.x, vb.y, vb.z, vb.w};
#pragma unroll
        for (int i = 0; i < 4; ++i) {
            int ch = cs + i;
            int cl = col ^ ((col & 32) >> 3) ^ (((ch >> 2) & 7) << 2);
            Bt[ch * 64 + cl] = fv[i];
        }
    }
    float xa[8];
    {
        const float* xap = xxf + bt * NP + n0 + rp * 8;
        float4 t0 = *(const float4*)xap;
        float4 t1 = *(const float4*)(xap + 4);
        xa[0]=t0.x; xa[1]=t0.y; xa[2]=t0.z; xa[3]=t0.w;
        xa[4]=t1.x; xa[5]=t1.y; xa[6]=t1.z; xa[7]=t1.w;
    }
    int r = tid >> 1, h = tid & 1;
    u64 v[16];
#pragma unroll
    for (int j = 0; j < 16; ++j) v[j] = 0;
    u64 q0 = 0, q1 = 0, q2 = 0, q3 = 0;
    int cnt = 0;
    u32 th32 = 0;
    int ab0 = (rp * 8) ^ (rp & 4);
    int ab1 = (rp * 8 + 4) ^ (rp & 4);
    int cb0 = (cg * 4) ^ ((cg & 8) >> 1);
    int swQ = ((r ^ (r >> 3)) & 7) << 2;
    __syncthreads();
#pragma unroll 1
    for (int mcl = 0; mcl < CHUNKS; ++mcl) {
        int m0c = m00 + (mcl << 6);
        bool more = (mcl + 1) < CHUNKS;
        float4 nv0, nv1, nv2, nv3;
        if (more) {
            const float* hn = hbase + ((size_t)(m0c + 64) << 6);
            nv0 = *(const float4*)(hn + ((0 * 16 + rp) << 6) + cs);
            nv1 = *(const float4*)(hn + ((1 * 16 + rp) << 6) + cs);
            nv2 = *(const float4*)(hn + ((2 * 16 + rp) << 6) + cs);
            nv3 = *(const float4*)(hn + ((3 * 16 + rp) << 6) + cs);
        }
        float4 xbv = *(const float4*)(xxf + bt * NP + m0c + (cg << 2));
        float acc[8][4];
#pragma unroll
        for (int i = 0; i < 8; ++i)
#pragma unroll
            for (int j = 0; j < 4; ++j) acc[i][j] = 0.f;
        // kk grouped by 4: swizzle + base addresses once per group; ascending kk
#pragma unroll 1
        for (int gI = 0; gI < 16; ++gI) {
            int sw = (gI & 7) << 2;
            const float* pa0 = At + (gI << 9) + (ab0 ^ sw);
            const float* pa1 = At + (gI << 9) + (ab1 ^ sw);
            const float* pbq = Bt + (gI << 8) + (cb0 ^ sw);
#pragma unroll
            for (int u = 0; u < 4; ++u) {
                float4 a0 = *(const float4*)(pa0 + (u << 7));
                float4 a1 = *(const float4*)(pa1 + (u << 7));
                float4 bq = *(const float4*)(pbq + (u << 6));
                float av[8] = {a0.x, a0.y, a0.z, a0.w, a1.x, a1.y, a1.z, a1.w};
                float bv[4] = {bq.x, bq.y, bq.z, bq.w};
#pragma unroll
                for (int i = 0; i < 8; ++i)
#pragma unroll
                    for (int j = 0; j < 4; ++j)
                        acc[i][j] = fmaf(av[i], bv[j], acc[i][j]);
            }
        }
        float xbs[4] = {xbv.x, xbv.y, xbv.z, xbv.w};
#pragma unroll
        for (int i = 0; i < 8; ++i) {
            int row = rp * 8 + i;
            u32 k0, k1, k2, k3;
            {
                float pd;
                pd = fmaf(2.0f, acc[i][0], -xa[i]) - xbs[0]; k0 = fmap(pd);
                pd = fmaf(2.0f, acc[i][1], -xa[i]) - xbs[1]; k1 = fmap(pd);
                pd = fmaf(2.0f, acc[i][2], -xa[i]) - xbs[2]; k2 = fmap(pd);
                pd = fmaf(2.0f, acc[i][3], -xa[i]) - xbs[3]; k3 = fmap(pd);
            }
            int sq = ((row ^ (row >> 3)) & 7) << 2;
            *(uint4*)(Sb + row * 64 + ((cg << 2) ^ sq)) = make_uint4(k0, k1, k2, k3);
        }
        __syncthreads();
#pragma unroll
        for (int sI = 0; sI < 8; ++sI) {
            int c0 = h * 32 + (sI << 2);
            uint4 kq = *(const uint4*)(Sb + r * 64 + (c0 ^ swQ));
            u32 m01 = kq.x > kq.y ? kq.x : kq.y;
            u32 m23 = kq.z > kq.w ? kq.z : kq.w;
            u32 mx = m01 > m23 ? m01 : m23;
            if (mx >= th32) {
                u32 ks[4] = {kq.x, kq.y, kq.z, kq.w};
#pragma unroll
                for (int j = 0; j < 4; ++j) {
                    if (ks[j] >= th32) {
                        u64 key = ((u64)ks[j] << 32) | (u64)(u32)~(m0c + c0 + j);
                        bufpush(v, q0, q1, q2, q3, cnt, key);
                    }
                }
            }
        }
        if (more) {
            float fva[4][4] = {{nv0.x, nv0.y, nv0.z, nv0.w}, {nv1.x, nv1.y, nv1.z, nv1.w},
                               {nv2.x, nv2.y, nv2.z, nv2.w}, {nv3.x, nv3.y, nv3.z, nv3.w}};
#pragma unroll
            for (int rep = 0; rep < 4; ++rep) {
                int col = rep * 16 + rp;
#pragma unroll
                for (int i = 0; i < 4; ++i) {
                    int ch = cs + i;
                    int cl = col ^ ((col & 32) >> 3) ^ (((ch >> 2) & 7) << 2);
                    Bt[ch * 64 + cl] = fva[rep][i];
                }
            }
        }
        if (__any(cnt >= 3)) {
            bufflush(v, q0, q1, q2, q3, cnt);
            u64 m = umax64(v[15], __shfl_xor(v[15], 1));
            th32 = (u32)(m >> 32);
        }
        __syncthreads();
    }
    bufflush(v, q0, q1, q2, q3, cnt);
    merge_shfl(v, 1);
    if (h == 0) {
        u64* op = partF + (((size_t)bt * NP + n0 + r) * SPLIT + seg) * 16;
#pragma unroll
        for (int j = 0; j < 16; ++j) op[j] = v[j];
    }
}

// --- fused: partF merge + edge5 combine (y=Z[m]+(C[n]-Z[n]), max) + conv1_4 GEMM ---
__global__ __launch_bounds__(256, 3) void edge5_gemm14_kernel(
        const float* __restrict__ ZC, const u64* __restrict__ partF,
        const float* __restrict__ g15, const float* __restrict__ bb15,
        const float* __restrict__ w14, const float* __restrict__ b14,
        const float* __restrict__ g14, const float* __restrict__ bb14,
        float* __restrict__ feat) {
    __shared__ int midx[64][16];      // 4KB
    __shared__ float Ag[64 * 65];     // 16.6KB  (g64t tile, pad 65)
    __shared__ float Wl[64 * 128];    // 32KB
    int tid = threadIdx.x;
#pragma unroll
    for (int i = 0; i < 8; ++i) {
        int f = tid + i * 256;
        *(float4*)(Wl + f * 4) = *(const float4*)(w14 + f * 4);
    }
    if (tid < 64) {   // merge the two seg partials for point blockIdx*64+tid
        int pt = blockIdx.x * 64 + tid;
        const u64* base = partF + (size_t)pt * (SPLIT * 16);
        u64 a[16];
#pragma unroll
        for (int j = 0; j < 16; ++j) a[j] = base[j];
#pragma unroll
        for (int j = 0; j < 16; ++j) {
            u64 x = base[16 + (15 - j)];
            a[j] = a[j] > x ? a[j] : x;
        }
        bclean(a);
#pragma unroll
        for (int j = 0; j < 16; ++j) midx[tid][j] = (int)~(u32)a[j];
    }
    __syncthreads();
    // edge5 combine: wave w handles points w*16..+15 sequentially; lane = channel
    int lane = tid & 63, w = tid >> 6;
    int bt = (blockIdx.x * 64) >> 12;   // 64-point tiles never straddle batches
    const float* zb = ZC + (((size_t)bt * NP) << 7);
    float sc = g15[lane] * INVBN, sh = bb15[lane];
#pragma unroll 1
    for (int pp = 0; pp < 16; ++pp) {
        int p = w * 16 + pp;
        int pt = blockIdx.x * 64 + p;
        const float* zrow = ZC + ((size_t)pt << 7);
        float zn = zrow[lane];
        float d = zrow[64 + lane] - zn;         // C[n] - Z[n]
        float zl[16];
#pragma unroll
        for (int j = 0; j < 16; ++j)
            zl[j] = zb[((size_t)midx[p][j] << 7) + lane];   // 16 loads in flight
        float a = -INFINITY;
#pragma unroll
        for (int j = 0; j < 16; ++j) {
            float z = fmaf(zl[j] + d, sc, sh);
            z = z >= 0.f ? z : 0.2f * z;
            a = fmaxf(a, z);
        }
        Ag[p * 65 + lane] = a;
    }
    __syncthreads();
    // conv1_4 GEMM (K=64, O=128, MODE1) from Ag — identical chain to old gemm14
    int po = tid & 7, pq = tid >> 3;
    int pt0 = pq * 2, o0 = po * 16;
    float acc[2][16];
#pragma unroll
    for (int i = 0; i < 16; ++i) { acc[0][i] = b14[o0 + i]; acc[1][i] = b14[o0 + i]; }
#pragma unroll 8
    for (int kk = 0; kk < 64; ++kk) {
        float a0 = Ag[pt0 * 65 + kk];
        float a1 = Ag[(pt0 + 1) * 65 + kk];
        float wv[16];
#pragma unroll
        for (int i4 = 0; i4 < 4; ++i4) {
            float4 t = *(const float4*)(Wl + kk * 128 + o0 + i4 * 4);
            wv[i4 * 4 + 0] = t.x; wv[i4 * 4 + 1] = t.y;
            wv[i4 * 4 + 2] = t.z; wv[i4 * 4 + 3] = t.w;
        }
#pragma unroll
        for (int i = 0; i < 16; ++i) {
            acc[0][i] = fmaf(a0, wv[i], acc[0][i]);
            acc[1][i] = fmaf(a1, wv[i], acc[1][i]);
        }
    }
#pragma unroll
    for (int p = 0; p < 2; ++p) {
        size_t rowg = (size_t)blockIdx.x * 64 + pt0 + p;
#pragma unroll
        for (int i4 = 0; i4 < 4; ++i4) {
            float4 ov;
#pragma unroll
            for (int j = 0; j < 4; ++j) {
                int o = o0 + i4 * 4 + j;
                float vv = fmaf(acc[p][i4 * 4 + j], g14[o] * INVBN, bb14[o]);
                ((float*)&ov)[j] = vv >= 0.f ? vv : 0.2f * vv;
            }
            *(float4*)(feat + rowg * 128 + o0 + i4 * 4) = ov;
        }
    }
}

// -------- fc head: fc1 (ReLU GEMM) + fc2 + refine --------
__global__ __launch_bounds__(256) void fc_head_kernel(const float* __restrict__ feat,
        const float* __restrict__ point,
        const float* __restrict__ wf1, const float* __restrict__ bf1,
        const float* __restrict__ wf2, const float* __restrict__ bf2,
        float* __restrict__ out) {
    __shared__ float A[64 * 129];     // 33KB
    __shared__ float Wl[128 * 64];    // 32KB; r[64][65] aliases after GEMM
    __shared__ float wf2l[192];
    float* R = Wl;
#pragma unroll
    for (int i = 0; i < 8; ++i) {
        int f = threadIdx.x + i * 256;
        int pt = f >> 5, c4 = f & 31;
        float4 v = *(const float4*)(feat + ((size_t)blockIdx.x * 64 + pt) * 128 + c4 * 4);
        float* d = A + pt * 129 + c4 * 4;
        d[0] = v.x; d[1] = v.y; d[2] = v.z; d[3] = v.w;
    }
#pragma unroll
    for (int i = 0; i < 8; ++i) {
        int f = threadIdx.x + i * 256;
        *(float4*)(Wl + f * 4) = *(const float4*)(wf1 + f * 4);
    }
    if (threadIdx.x < 48)
        *(float4*)(wf2l + threadIdx.x * 4) = *(const float4*)(wf2 + threadIdx.x * 4);
    __syncthreads();
    int po = threadIdx.x & 7, pp = threadIdx.x >> 3;
    int pt0 = pp * 2, o0 = po * 8;
    float acc[2][8];
#pragma unroll
    for (int i = 0; i < 8; ++i) { acc[0][i] = bf1[o0 + i]; acc[1][i] = bf1[o0 + i]; }
#pragma unroll 8
    for (int kk = 0; kk < 128; ++kk) {
        float a0 = A[pt0 * 129 + kk];
        float a1 = A[(pt0 + 1) * 129 + kk];
        float w[8];
#pragma unroll
        for (int i4 = 0; i4 < 2; ++i4) {
            float4 wv = *(const float4*)(Wl + kk * 64 + o0 + i4 * 4);
            w[i4 * 4 + 0] = wv.x; w[i4 * 4 + 1] = wv.y;
            w[i4 * 4 + 2] = wv.z; w[i4 * 4 + 3] = wv.w;
        }
#pragma unroll
        for (int i = 0; i < 8; ++i) {
            acc[0][i] = fmaf(a0, w[i], acc[0][i]);
            acc[1][i] = fmaf(a1, w[i], acc[1][i]);
        }
    }
    __syncthreads();   // all Wl reads done; R may alias
#pragma unroll
    for (int p = 0; p < 2; ++p)
#pragma unroll
        for (int i = 0; i < 8; ++i)
            R[(pt0 + p) * 65 + o0 + i] = fmaxf(acc[p][i], 0.f);
    __syncthreads();
    if (threadIdx.x < 192) {
        int pt = threadIdx.x / 3, dim = threadIdx.x - pt * 3;
        float ssum = 0.f;
#pragma unroll
        for (int c = 0; c < 64; ++c)
            ssum = fmaf(R[pt * 65 + c], wf2l[c * 3 + dim], ssum);
        int ptg = blockIdx.x * 64 + pt;
        int bt = ptg >> 12, n = ptg & (NP - 1);
        float p = point[((size_t)bt * 3 + dim) * NP + n];
        out[(size_t)FEAT_SZ + (size_t)ptg * 3 + dim] = ssum + bf2[dim] + p;
    }
}

extern "C" void kernel_launch(void* const* d_in, const int* in_sizes, int n_in,
                              void* d_out, int out_size, void* d_ws, size_t ws_size,
                              hipStream_t stream) {
    (void)in_sizes; (void)n_in; (void)out_size; (void)ws_size;
    const float* point = (const float*)d_in[0];
    const float* w11 = (const float*)d_in[1];
    const float* b11 = (const float*)d_in[2];
    const float* g11 = (const float*)d_in[3];
    const float* bb11 = (const float*)d_in[4];
    const float* w12 = (const float*)d_in[5];
    const float* b12 = (const float*)d_in[6];
    const float* g12 = (const float*)d_in[7];
    const float* bb12 = (const float*)d_in[8];
    const float* w13 = (const float*)d_in[9];
    const float* b13 = (const float*)d_in[10];
    const float* g13 = (const float*)d_in[11];
    const float* bb13 = (const float*)d_in[12];
    const float* w15 = (const float*)d_in[13];
    const float* b15 = (const float*)d_in[14];
    const float* g15 = (const float*)d_in[15];
    const float* bb15 = (const float*)d_in[16];
    const float* w14 = (const float*)d_in[17];
    const float* b14 = (const float*)d_in[18];
    const float* g14 = (const float*)d_in[19];
    const float* bb14 = (const float*)d_in[20];
    const float* wf1 = (const float*)d_in[21];
    const float* bf1 = (const float*)d_in[22];
    const float* wf2 = (const float*)d_in[23];
    const float* bf2 = (const float*)d_in[24];

    // ws layout with lifetime aliasing:
    //  2..2.25: xxf
    //  4..12  : h1t
    //  12..20 : partF
    //  20..36 : f12 -> ZC (f12 dead after gemm13)
    char* ws = (char*)d_ws;
    float* xxf   = (float*)(ws + (2u << 20));
    float* h1t   = (float*)(ws + (4u << 20));
    u64*   partF = (u64*)(ws + (12u << 20));
    float* f12   = (float*)(ws + (20u << 20));
    float* ZC    = (float*)(ws + (20u << 20));
    float* feat  = (float*)d_out;                 // [B*N][128]

    knn_point_edge12_kernel<<<dim3(NB * 128), dim3(256), 0, stream>>>(
        point, w11, b11, g11, bb11, w12, b12, g12, bb12, f12);
    gemm_act_kernel<128, 64, 1, true><<<dim3(NB * NP / 64), dim3(256), 0, stream>>>(
        f12, w13, b13, g13, bb13, h1t, xxf);
    knn_feat_kernel<<<dim3(NB * 32 * SPLIT), dim3(256), 0, stream>>>(h1t, xxf, partF);
    gemm_act_kernel<64, 128, 0, false><<<dim3(NB * NP / 64), dim3(256), 0, stream>>>(
        h1t, w15, b15, nullptr, nullptr, ZC, nullptr);
    edge5_gemm14_kernel<<<dim3(NB * NP / 64), dim3(256), 0, stream>>>(
        ZC, partF, g15, bb15, w14, b14, g14, bb14, feat);
    fc_head_kernel<<<dim3(NB * NP / 64), dim3(256), 0, stream>>>(
        feat, point, wf1, bf1, wf2, bf2, (float*)d_out);
}

// Round 13
// 945.463 us; speedup vs baseline: 1.0207x; 1.0207x over previous
//
#include <hip/hip_runtime.h>
#include <math.h>

#define NB 8
#define NP 4096
#define FEAT_SZ (NB * NP * 128)
#define INVBN 0.9999950000374999f  // 1/sqrt(1+1e-5), f32-rounded
#define SPLIT 2
#define CHUNKS 32                  // 4096 cols / 64 / SPLIT

typedef unsigned long long u64;
typedef unsigned int u32;

// monotone map: float -> u32 preserving order (larger float -> larger u32)
__device__ __forceinline__ u32 fmap(float f) {
    u32 b = __float_as_uint(f);
    return b ^ ((u32)((int)b >> 31) | 0x80000000u);
}

__device__ __forceinline__ u64 umax64(u64 a, u64 b) { return a > b ? a : b; }

// insert key into descending-sorted v[16] if it beats the current 16th.
__device__ __forceinline__ void kins(u64 (&v)[16], u64 key) {
    if (key <= v[15]) return;
    bool bb[16];
#pragma unroll
    for (int j = 0; j < 16; ++j) bb[j] = key > v[j];
#pragma unroll
    for (int j = 15; j >= 1; --j) v[j] = bb[j] ? (bb[j - 1] ? v[j - 1] : key) : v[j];
    if (bb[0]) v[0] = key;
}

__device__ __forceinline__ void bufpush(u64 (&v)[16], u64 &q0, u64 &q1, u64 &q2, u64 &q3,
                                        int &cnt, u64 key) {
    if (cnt < 4) {
        q0 = cnt == 0 ? key : q0;
        q1 = cnt == 1 ? key : q1;
        q2 = cnt == 2 ? key : q2;
        q3 = cnt == 3 ? key : q3;
        ++cnt;
    } else {
        kins(v, key);   // rare overflow fallback (exactness guarantee)
    }
}

__device__ __forceinline__ void bufflush(u64 (&v)[16], u64 &q0, u64 &q1, u64 &q2, u64 &q3,
                                         int &cnt) {
    kins(v, q0); kins(v, q1); kins(v, q2); kins(v, q3);
    q0 = 0; q1 = 0; q2 = 0; q3 = 0; cnt = 0;
}

// bitonic clean (desc) of a bitonic 16-sequence -> fully sorted desc
__device__ __forceinline__ void bclean(u64 (&v)[16]) {
#pragma unroll
    for (int d = 8; d; d >>= 1) {
#pragma unroll
        for (int i = 0; i < 16; ++i) {
            if ((i & d) == 0) {
                u64 a = v[i], b = v[i | d];
                bool s = a < b;
                v[i] = s ? b : a;
                v[i | d] = s ? a : b;
            }
        }
    }
}

__device__ __forceinline__ void merge_shfl(u64 (&v)[16], int off) {
    u64 o[16];
#pragma unroll
    for (int j = 0; j < 16; ++j) o[j] = __shfl_down(v[j], off);
#pragma unroll
    for (int j = 0; j < 16; ++j) {
        u64 b = o[15 - j];
        v[j] = v[j] > b ? v[j] : b;
    }
    bclean(v);
}

__device__ __forceinline__ u64 rowmax8(u64 x) {
    x = umax64(x, __shfl_xor(x, 1));
    x = umax64(x, __shfl_xor(x, 2));
    x = umax64(x, __shfl_xor(x, 4));
    return x;
}

// ---------------- kernel A: point-space kNN (k=16) ----------------
__global__ __launch_bounds__(256) void knn_point_kernel(const float* __restrict__ point,
                                                        int* __restrict__ idxP) {
    __shared__ float4 pts[NP];  // (x,y,z,xx)  64 KiB
    int bt = blockIdx.x >> 7;
    int n0 = (blockIdx.x & 127) << 5;
    const float* pb = point + (size_t)bt * 3 * NP;
    for (int m = threadIdx.x; m < NP; m += 256) {
        float x = pb[m], y = pb[NP + m], z = pb[2 * NP + m];
        pts[m] = make_float4(x, y, z, fmaf(z, z, fmaf(y, y, x * x)));
    }
    __syncthreads();
    int t = threadIdx.x;
    int q = t & 7;
    float4 c = pts[n0 + (t >> 3)];
    u64 v[16];
#pragma unroll
    for (int j = 0; j < 16; ++j) v[j] = 0;
    u64 b0 = 0, b1 = 0, b2 = 0, b3 = 0;
    int cnt = 0;
    u64 th = 0;
#pragma unroll 1
    for (int o = 0; o < 8; ++o) {
#pragma unroll 4
        for (int ii = 0; ii < 64; ++ii) {
            int m = (((o << 6) + ii) << 3) + q;
            float4 p = pts[m];
            float inner = fmaf(c.z, p.z, fmaf(c.y, p.y, c.x * p.x));
            float pd = fmaf(2.0f, inner, -c.w) - p.w;  // 2*inner - xx_n - xx_m
            u64 key = ((u64)fmap(pd) << 32) | (u64)(u32)~m;
            if (key > th) bufpush(v, b0, b1, b2, b3, cnt, key);
        }
        if (__any(cnt >= 3)) {
            bufflush(v, b0, b1, b2, b3, cnt);
            th = rowmax8(v[15]);
        }
    }
    bufflush(v, b0, b1, b2, b3, cnt);
    merge_shfl(v, 4);
    merge_shfl(v, 2);
    merge_shfl(v, 1);
    if (q == 0) {
        int* op = idxP + ((size_t)bt * NP + n0 + (t >> 3)) * 16;
#pragma unroll
        for (int j = 0; j < 16; ++j) op[j] = (int)~(u32)v[j];
    }
}

// ---------- kernel B: edge-conv1_1(k=8) + 1_2(k=16) -> f12 [n][128] ----------
__global__ __launch_bounds__(256) void edge12_kernel(
    const float* __restrict__ point, const int* __restrict__ idxP,
    const float* __restrict__ w11, const float* __restrict__ b11,
    const float* __restrict__ g11, const float* __restrict__ bb11,
    const float* __restrict__ w12, const float* __restrict__ b12,
    const float* __restrict__ g12, const float* __restrict__ bb12,
    float* __restrict__ f12) {
    int lane = threadIdx.x & 63;
    int pt = blockIdx.x * 4 + (threadIdx.x >> 6);
    int bt = pt >> 12, n = pt & (NP - 1);
    const float* pb = point + (size_t)bt * 3 * NP;
    float wd1[3], wc1[3], wd2[3], wc2[3];
#pragma unroll
    for (int c = 0; c < 3; ++c) {
        wd1[c] = w11[c * 64 + lane]; wc1[c] = w11[(3 + c) * 64 + lane];
        wd2[c] = w12[c * 64 + lane]; wc2[c] = w12[(3 + c) * 64 + lane];
    }
    float s1 = g11[lane] * INVBN, sh1 = bb11[lane];
    float s2 = g12[lane] * INVBN, sh2 = bb12[lane];
    float cx = pb[n], cy = pb[NP + n], cz = pb[2 * NP + n];
    float base1 = fmaf(wc1[2], cz, fmaf(wc1[1], cy, fmaf(wc1[0], cx, b11[lane])));
    float base2 = fmaf(wc2[2], cz, fmaf(wc2[1], cy, fmaf(wc2[0], cx, b12[lane])));
    float a1 = -INFINITY, a2 = -INFINITY;
    const int* nb = idxP + (size_t)pt * 16;
#pragma unroll
    for (int j = 0; j < 16; ++j) {
        int m = nb[j];
        float ex = pb[m] - cx, ey = pb[NP + m] - cy, ez = pb[2 * NP + m] - cz;
        float y2 = fmaf(wd2[2], ez, fmaf(wd2[1], ey, fmaf(wd2[0], ex, base2)));
        float z2 = fmaf(y2, s2, sh2);
        z2 = z2 >= 0.f ? z2 : 0.2f * z2;
        a2 = fmaxf(a2, z2);
        if (j < 8) {  // top-8 is prefix of sorted top-16
            float y1 = fmaf(wd1[2], ez, fmaf(wd1[1], ey, fmaf(wd1[0], ex, base1)));
            float z1 = fmaf(y1, s1, sh1);
            z1 = z1 >= 0.f ? z1 : 0.2f * z1;
            a1 = fmaxf(a1, z1);
        }
    }
    f12[((size_t)pt << 7) + lane] = a1;
    f12[((size_t)pt << 7) + 64 + lane] = a2;
}

// ---------------- generic register-tiled GEMM + activation ----------------
template<int K, int O, int MODE, bool XX>
__global__ __launch_bounds__(256) void gemm_act_kernel(
        const float* __restrict__ in, const float* __restrict__ W,
        const float* __restrict__ b, const float* __restrict__ g,
        const float* __restrict__ s, float* __restrict__ outp,
        float* __restrict__ xxo) {
    __shared__ __align__(16) char smem[64 * (K + 1) * 4 + K * O * 4];
    float* A  = (float*)smem;
    float* Wl = (float*)(smem + 64 * (K + 1) * 4);
    float* Hs = (float*)smem;   // [64][65] alias over A (used only when XX, after barrier)
    constexpr int F4R = K / 4;
#pragma unroll
    for (int i = 0; i < 64 * F4R / 256; ++i) {
        int f = threadIdx.x + i * 256;
        int pt = f / F4R, c4 = f % F4R;
        float4 v = *(const float4*)(in + ((size_t)blockIdx.x * 64 + pt) * K + c4 * 4);
        float* d = A + pt * (K + 1) + c4 * 4;
        d[0] = v.x; d[1] = v.y; d[2] = v.z; d[3] = v.w;
    }
    if constexpr (MODE == 0) {
#pragma unroll
        for (int i = 0; i < 8; ++i) {
            int f = threadIdx.x + i * 256;
            int half = f >= 1024;
            int fr = f & 1023;
            int c = fr >> 4, o4 = fr & 15;
            const float* src = half ? (W + (64 + c) * 64 + o4 * 4) : (W + c * 64 + o4 * 4);
            float4 v = *(const float4*)src;
            float* d = Wl + c * 128 + half * 64 + o4 * 4;
            d[0] = v.x; d[1] = v.y; d[2] = v.z; d[3] = v.w;
        }
    } else {
#pragma unroll
        for (int i = 0; i < K * O / 1024; ++i) {
            int f = threadIdx.x + i * 256;
            *(float4*)(Wl + f * 4) = *(const float4*)(W + f * 4);
        }
    }
    __syncthreads();
    constexpr int NO = O / 8;
    int po = threadIdx.x & 7, pp = threadIdx.x >> 3;
    int pt0 = pp * 2, o0 = po * NO;
    float acc[2][NO];
#pragma unroll
    for (int i = 0; i < NO; ++i) {
        int o = o0 + i;
        float init;
        if constexpr (MODE == 0) init = (o < 64) ? 0.f : b[o - 64];
        else init = b[o];
        acc[0][i] = init;
        acc[1][i] = init;
    }
#pragma unroll 8
    for (int kk = 0; kk < K; ++kk) {
        float a0 = A[pt0 * (K + 1) + kk];
        float a1 = A[(pt0 + 1) * (K + 1) + kk];
        float w[NO];
#pragma unroll
        for (int i4 = 0; i4 < NO / 4; ++i4) {
            float4 wv = *(const float4*)(Wl + kk * O + o0 + i4 * 4);
            w[i4 * 4 + 0] = wv.x; w[i4 * 4 + 1] = wv.y;
            w[i4 * 4 + 2] = wv.z; w[i4 * 4 + 3] = wv.w;
        }
#pragma unroll
        for (int i = 0; i < NO; ++i) {
            acc[0][i] = fmaf(a0, w[i], acc[0][i]);   // ascending-k chain
            acc[1][i] = fmaf(a1, w[i], acc[1][i]);
        }
    }
    float tact[2][NO];
#pragma unroll
    for (int p = 0; p < 2; ++p) {
#pragma unroll
        for (int i = 0; i < NO; ++i) {
            int o = o0 + i;
            float a = acc[p][i];
            if constexpr (MODE == 0) {
                tact[p][i] = a;
            } else {
                float vv = fmaf(a, g[o] * INVBN, s[o]);
                tact[p][i] = vv >= 0.f ? vv : 0.2f * vv;
            }
        }
    }
#pragma unroll
    for (int p = 0; p < 2; ++p) {
        size_t rowg = (size_t)blockIdx.x * 64 + pt0 + p;
#pragma unroll
        for (int i4 = 0; i4 < NO / 4; ++i4) {
            float4 ov;
            ov.x = tact[p][i4 * 4 + 0]; ov.y = tact[p][i4 * 4 + 1];
            ov.z = tact[p][i4 * 4 + 2]; ov.w = tact[p][i4 * 4 + 3];
            *(float4*)(outp + rowg * O + o0 + i4 * 4) = ov;
        }
    }
    if constexpr (XX) {
        __syncthreads();   // all A reads done; Hs may alias A now
#pragma unroll
        for (int p = 0; p < 2; ++p)
#pragma unroll
            for (int i = 0; i < NO; ++i)
                Hs[(pt0 + p) * 65 + o0 + i] = tact[p][i];
        __syncthreads();
        if (threadIdx.x < 64) {
            float ss = 0.f;
#pragma unroll
            for (int c = 0; c < 64; ++c) {
                float hc = Hs[threadIdx.x * 65 + c];
                ss = fmaf(hc, hc, ss);   // ascending-c chain == old xxf chain
            }
            xxo[(size_t)blockIdx.x * 64 + threadIdx.x] = ss;
        }
    }
}

// ---------------- kernel C: feature-space kNN (C=64, k=16) ----------------
// 128 rows x 64 cols/chunk, 80KB LDS (proven-best structure).
__global__ __launch_bounds__(256, 2) void knn_feat_kernel(const float* __restrict__ h1t,
                                                          const float* __restrict__ xxf,
                                                          u64* __restrict__ partF) {
    __shared__ __align__(16) char smem[81920];
    float* At = (float*)smem;                  // [64ch][128row swizzled] 32KB
    float* Bt = (float*)(smem + 32768);        // [64ch][64col swizzled]  16KB
    u32*   Sb = (u32*)(smem + 49152);          // [128row][64col swizzled] 32KB
    int seg = blockIdx.x & 1;
    int rg  = (blockIdx.x >> 1) & 31;
    int bt  = blockIdx.x >> 6;
    int n0  = rg << 7;
    int tid = threadIdx.x;
    int rp = tid >> 4;
    int cg = tid & 15;
    int cs = cg << 2;
    const float* hbase = h1t + ((size_t)bt * NP << 6);
    const float* hA = hbase + ((size_t)n0 << 6);
#pragma unroll
    for (int rep = 0; rep < 8; ++rep) {
        int row = rep * 16 + rp;
        float4 va = *(const float4*)(hA + (row << 6) + cs);
        float fv[4] = {va.x, va.y, va.z, va.w};
#pragma unroll
        for (int i = 0; i < 4; ++i) {
            int ch = cs + i;
            int rw = row ^ ((row & 32) >> 3) ^ (((ch >> 2) & 7) << 2);
            At[ch * 128 + rw] = fv[i];
        }
    }
    int m00 = seg * (CHUNKS * 64);
#pragma unroll
    for (int rep = 0; rep < 4; ++rep) {
        int col = rep * 16 + rp;
        float4 vb = *(const float4*)(hbase + ((size_t)(m00 + col) << 6) + cs);
        float fv[4] = {vb.x, vb.y, vb.z, vb.w};
#pragma unroll
        for (int i = 0; i < 4; ++i) {
            int ch = cs + i;
            int cl = col ^ ((col & 32) >> 3) ^ (((ch >> 2) & 7) << 2);
            Bt[ch * 64 + cl] = fv[i];
        }
    }
    float xa[8];
    {
        const float* xap = xxf + bt * NP + n0 + rp * 8;
        float4 t0 = *(const float4*)xap;
        float4 t1 = *(const float4*)(xap + 4);
        xa[0]=t0.x; xa[1]=t0.y; xa[2]=t0.z; xa[3]=t0.w;
        xa[4]=t1.x; xa[5]=t1.y; xa[6]=t1.z; xa[7]=t1.w;
    }
    int r = tid >> 1, h = tid & 1;
    u64 v[16];
#pragma unroll
    for (int j = 0; j < 16; ++j) v[j] = 0;
    u64 q0 = 0, q1 = 0, q2 = 0, q3 = 0;
    int cnt = 0;
    u32 th32 = 0;
    int ab0 = (rp * 8) ^ (rp & 4);
    int ab1 = (rp * 8 + 4) ^ (rp & 4);
    int cb0 = (cg * 4) ^ ((cg & 8) >> 1);
    int swQ = ((r ^ (r >> 3)) & 7) << 2;
    __syncthreads();
#pragma unroll 1
    for (int mcl = 0; mcl < CHUNKS; ++mcl) {
        int m0c = m00 + (mcl << 6);
        bool more = (mcl + 1) < CHUNKS;
        float4 nv0, nv1, nv2, nv3;
        if (more) {
            const float* hn = hbase + ((size_t)(m0c + 64) << 6);
            nv0 = *(const float4*)(hn + ((0 * 16 + rp) << 6) + cs);
            nv1 = *(const float4*)(hn + ((1 * 16 + rp) << 6) + cs);
            nv2 = *(const float4*)(hn + ((2 * 16 + rp) << 6) + cs);
            nv3 = *(const float4*)(hn + ((3 * 16 + rp) << 6) + cs);
        }
        float4 xbv = *(const float4*)(xxf + bt * NP + m0c + (cg << 2));
        float acc[8][4];
#pragma unroll
        for (int i = 0; i < 8; ++i)
#pragma unroll
            for (int j = 0; j < 4; ++j) acc[i][j] = 0.f;
        // kk grouped by 4: swizzle + base addresses once per group; ascending kk
#pragma unroll 1
        for (int gI = 0; gI < 16; ++gI) {
            int sw = (gI & 7) << 2;
            const float* pa0 = At + (gI << 9) + (ab0 ^ sw);
            const float* pa1 = At + (gI << 9) + (ab1 ^ sw);
            const float* pbq = Bt + (gI << 8) + (cb0 ^ sw);
#pragma unroll
            for (int u = 0; u < 4; ++u) {
                float4 a0 = *(const float4*)(pa0 + (u << 7));
                float4 a1 = *(const float4*)(pa1 + (u << 7));
                float4 bq = *(const float4*)(pbq + (u << 6));
                float av[8] = {a0.x, a0.y, a0.z, a0.w, a1.x, a1.y, a1.z, a1.w};
                float bv[4] = {bq.x, bq.y, bq.z, bq.w};
#pragma unroll
                for (int i = 0; i < 8; ++i)
#pragma unroll
                    for (int j = 0; j < 4; ++j)
                        acc[i][j] = fmaf(av[i], bv[j], acc[i][j]);
            }
        }
        float xbs[4] = {xbv.x, xbv.y, xbv.z, xbv.w};
#pragma unroll
        for (int i = 0; i < 8; ++i) {
            int row = rp * 8 + i;
            u32 k0, k1, k2, k3;
            {
                float pd;
                pd = fmaf(2.0f, acc[i][0], -xa[i]) - xbs[0]; k0 = fmap(pd);
                pd = fmaf(2.0f, acc[i][1], -xa[i]) - xbs[1]; k1 = fmap(pd);
                pd = fmaf(2.0f, acc[i][2], -xa[i]) - xbs[2]; k2 = fmap(pd);
                pd = fmaf(2.0f, acc[i][3], -xa[i]) - xbs[3]; k3 = fmap(pd);
            }
            int sq = ((row ^ (row >> 3)) & 7) << 2;
            *(uint4*)(Sb + row * 64 + ((cg << 2) ^ sq)) = make_uint4(k0, k1, k2, k3);
        }
        __syncthreads();
#pragma unroll
        for (int sI = 0; sI < 8; ++sI) {
            int c0 = h * 32 + (sI << 2);
            uint4 kq = *(const uint4*)(Sb + r * 64 + (c0 ^ swQ));
            u32 m01 = kq.x > kq.y ? kq.x : kq.y;
            u32 m23 = kq.z > kq.w ? kq.z : kq.w;
            u32 mx = m01 > m23 ? m01 : m23;
            if (mx >= th32) {
                u32 ks[4] = {kq.x, kq.y, kq.z, kq.w};
#pragma unroll
                for (int j = 0; j < 4; ++j) {
                    if (ks[j] >= th32) {
                        u64 key = ((u64)ks[j] << 32) | (u64)(u32)~(m0c + c0 + j);
                        bufpush(v, q0, q1, q2, q3, cnt, key);
                    }
                }
            }
        }
        if (more) {
            float fva[4][4] = {{nv0.x, nv0.y, nv0.z, nv0.w}, {nv1.x, nv1.y, nv1.z, nv1.w},
                               {nv2.x, nv2.y, nv2.z, nv2.w}, {nv3.x, nv3.y, nv3.z, nv3.w}};
#pragma unroll
            for (int rep = 0; rep < 4; ++rep) {
                int col = rep * 16 + rp;
#pragma unroll
                for (int i = 0; i < 4; ++i) {
                    int ch = cs + i;
                    int cl = col ^ ((col & 32) >> 3) ^ (((ch >> 2) & 7) << 2);
                    Bt[ch * 64 + cl] = fva[rep][i];
                }
            }
        }
        if (__any(cnt >= 3)) {
            bufflush(v, q0, q1, q2, q3, cnt);
            u64 m = umax64(v[15], __shfl_xor(v[15], 1));
            th32 = (u32)(m >> 32);
        }
        __syncthreads();
    }
    bufflush(v, q0, q1, q2, q3, cnt);
    merge_shfl(v, 1);
    if (h == 0) {
        u64* op = partF + (((size_t)bt * NP + n0 + r) * SPLIT + seg) * 16;
#pragma unroll
        for (int j = 0; j < 16; ++j) op[j] = v[j];
    }
}

// --- fused: partF merge + edge5 combine (y=Z[m]+(C[n]-Z[n]), max) + conv1_4 GEMM ---
__global__ __launch_bounds__(256, 3) void edge5_gemm14_kernel(
        const float* __restrict__ ZC, const u64* __restrict__ partF,
        const float* __restrict__ g15, const float* __restrict__ bb15,
        const float* __restrict__ w14, const float* __restrict__ b14,
        const float* __restrict__ g14, const float* __restrict__ bb14,
        float* __restrict__ feat) {
    __shared__ int midx[64][16];      // 4KB
    __shared__ float Ag[64 * 65];     // 16.6KB  (g64t tile, pad 65)
    __shared__ float Wl[64 * 128];    // 32KB
    int tid = threadIdx.x;
#pragma unroll
    for (int i = 0; i < 8; ++i) {
        int f = tid + i * 256;
        *(float4*)(Wl + f * 4) = *(const float4*)(w14 + f * 4);
    }
    if (tid < 64) {   // merge the two seg partials for point blockIdx*64+tid
        int pt = blockIdx.x * 64 + tid;
        const u64* base = partF + (size_t)pt * (SPLIT * 16);
        u64 a[16];
#pragma unroll
        for (int j = 0; j < 16; ++j) a[j] = base[j];
#pragma unroll
        for (int j = 0; j < 16; ++j) {
            u64 x = base[16 + (15 - j)];
            a[j] = a[j] > x ? a[j] : x;
        }
        bclean(a);
#pragma unroll
        for (int j = 0; j < 16; ++j) midx[tid][j] = (int)~(u32)a[j];
    }
    __syncthreads();
    // edge5 combine: wave w handles points w*16..+15 sequentially; lane = channel
    int lane = tid & 63, w = tid >> 6;
    int bt = (blockIdx.x * 64) >> 12;   // 64-point tiles never straddle batches
    const float* zb = ZC + (((size_t)bt * NP) << 7);
    float sc = g15[lane] * INVBN, sh = bb15[lane];
#pragma unroll 1
    for (int pp = 0; pp < 16; ++pp) {
        int p = w * 16 + pp;
        int pt = blockIdx.x * 64 + p;
        const float* zrow = ZC + ((size_t)pt << 7);
        float zn = zrow[lane];
        float d = zrow[64 + lane] - zn;         // C[n] - Z[n]
        float zl[16];
#pragma unroll
        for (int j = 0; j < 16; ++j)
            zl[j] = zb[((size_t)midx[p][j] << 7) + lane];   // 16 loads in flight
        float a = -INFINITY;
#pragma unroll
        for (int j = 0; j < 16; ++j) {
            float z = fmaf(zl[j] + d, sc, sh);
            z = z >= 0.f ? z : 0.2f * z;
            a = fmaxf(a, z);
        }
        Ag[p * 65 + lane] = a;
    }
    __syncthreads();
    // conv1_4 GEMM (K=64, O=128, MODE1) from Ag — identical chain to old gemm14
    int po = tid & 7, pq = tid >> 3;
    int pt0 = pq * 2, o0 = po * 16;
    float acc[2][16];
#pragma unroll
    for (int i = 0; i < 16; ++i) { acc[0][i] = b14[o0 + i]; acc[1][i] = b14[o0 + i]; }
#pragma unroll 8
    for (int kk = 0; kk < 64; ++kk) {
        float a0 = Ag[pt0 * 65 + kk];
        float a1 = Ag[(pt0 + 1) * 65 + kk];
        float wv[16];
#pragma unroll
        for (int i4 = 0; i4 < 4; ++i4) {
            float4 t = *(const float4*)(Wl + kk * 128 + o0 + i4 * 4);
            wv[i4 * 4 + 0] = t.x; wv[i4 * 4 + 1] = t.y;
            wv[i4 * 4 + 2] = t.z; wv[i4 * 4 + 3] = t.w;
        }
#pragma unroll
        for (int i = 0; i < 16; ++i) {
            acc[0][i] = fmaf(a0, wv[i], acc[0][i]);
            acc[1][i] = fmaf(a1, wv[i], acc[1][i]);
        }
    }
#pragma unroll
    for (int p = 0; p < 2; ++p) {
        size_t rowg = (size_t)blockIdx.x * 64 + pt0 + p;
#pragma unroll
        for (int i4 = 0; i4 < 4; ++i4) {
            float4 ov;
#pragma unroll
            for (int j = 0; j < 4; ++j) {
                int o = o0 + i4 * 4 + j;
                float vv = fmaf(acc[p][i4 * 4 + j], g14[o] * INVBN, bb14[o]);
                ((float*)&ov)[j] = vv >= 0.f ? vv : 0.2f * vv;
            }
            *(float4*)(feat + rowg * 128 + o0 + i4 * 4) = ov;
        }
    }
}

// -------- fc head: fc1 (ReLU GEMM) + fc2 + refine --------
__global__ __launch_bounds__(256) void fc_head_kernel(const float* __restrict__ feat,
        const float* __restrict__ point,
        const float* __restrict__ wf1, const float* __restrict__ bf1,
        const float* __restrict__ wf2, const float* __restrict__ bf2,
        float* __restrict__ out) {
    __shared__ float A[64 * 129];     // 33KB
    __shared__ float Wl[128 * 64];    // 32KB; r[64][65] aliases after GEMM
    __shared__ float wf2l[192];
    float* R = Wl;
#pragma unroll
    for (int i = 0; i < 8; ++i) {
        int f = threadIdx.x + i * 256;
        int pt = f >> 5, c4 = f & 31;
        float4 v = *(const float4*)(feat + ((size_t)blockIdx.x * 64 + pt) * 128 + c4 * 4);
        float* d = A + pt * 129 + c4 * 4;
        d[0] = v.x; d[1] = v.y; d[2] = v.z; d[3] = v.w;
    }
#pragma unroll
    for (int i = 0; i < 8; ++i) {
        int f = threadIdx.x + i * 256;
        *(float4*)(Wl + f * 4) = *(const float4*)(wf1 + f * 4);
    }
    if (threadIdx.x < 48)
        *(float4*)(wf2l + threadIdx.x * 4) = *(const float4*)(wf2 + threadIdx.x * 4);
    __syncthreads();
    int po = threadIdx.x & 7, pp = threadIdx.x >> 3;
    int pt0 = pp * 2, o0 = po * 8;
    float acc[2][8];
#pragma unroll
    for (int i = 0; i < 8; ++i) { acc[0][i] = bf1[o0 + i]; acc[1][i] = bf1[o0 + i]; }
#pragma unroll 8
    for (int kk = 0; kk < 128; ++kk) {
        float a0 = A[pt0 * 129 + kk];
        float a1 = A[(pt0 + 1) * 129 + kk];
        float w[8];
#pragma unroll
        for (int i4 = 0; i4 < 2; ++i4) {
            float4 wv = *(const float4*)(Wl + kk * 64 + o0 + i4 * 4);
            w[i4 * 4 + 0] = wv.x; w[i4 * 4 + 1] = wv.y;
            w[i4 * 4 + 2] = wv.z; w[i4 * 4 + 3] = wv.w;
        }
#pragma unroll
        for (int i = 0; i < 8; ++i) {
            acc[0][i] = fmaf(a0, w[i], acc[0][i]);
            acc[1][i] = fmaf(a1, w[i], acc[1][i]);
        }
    }
    __syncthreads();   // all Wl reads done; R may alias
#pragma unroll
    for (int p = 0; p < 2; ++p)
#pragma unroll
        for (int i = 0; i < 8; ++i)
            R[(pt0 + p) * 65 + o0 + i] = fmaxf(acc[p][i], 0.f);
    __syncthreads();
    if (threadIdx.x < 192) {
        int pt = threadIdx.x / 3, dim = threadIdx.x - pt * 3;
        float ssum = 0.f;
#pragma unroll
        for (int c = 0; c < 64; ++c)
            ssum = fmaf(R[pt * 65 + c], wf2l[c * 3 + dim], ssum);
        int ptg = blockIdx.x * 64 + pt;
        int bt = ptg >> 12, n = ptg & (NP - 1);
        float p = point[((size_t)bt * 3 + dim) * NP + n];
        out[(size_t)FEAT_SZ + (size_t)ptg * 3 + dim] = ssum + bf2[dim] + p;
    }
}

extern "C" void kernel_launch(void* const* d_in, const int* in_sizes, int n_in,
                              void* d_out, int out_size, void* d_ws, size_t ws_size,
                              hipStream_t stream) {
    (void)in_sizes; (void)n_in; (void)out_size; (void)ws_size;
    const float* point = (const float*)d_in[0];
    const float* w11 = (const float*)d_in[1];
    const float* b11 = (const float*)d_in[2];
    const float* g11 = (const float*)d_in[3];
    const float* bb11 = (const float*)d_in[4];
    const float* w12 = (const float*)d_in[5];
    const float* b12 = (const float*)d_in[6];
    const float* g12 = (const float*)d_in[7];
    const float* bb12 = (const float*)d_in[8];
    const float* w13 = (const float*)d_in[9];
    const float* b13 = (const float*)d_in[10];
    const float* g13 = (const float*)d_in[11];
    const float* bb13 = (const float*)d_in[12];
    const float* w15 = (const float*)d_in[13];
    const float* b15 = (const float*)d_in[14];
    const float* g15 = (const float*)d_in[15];
    const float* bb15 = (const float*)d_in[16];
    const float* w14 = (const float*)d_in[17];
    const float* b14 = (const float*)d_in[18];
    const float* g14 = (const float*)d_in[19];
    const float* bb14 = (const float*)d_in[20];
    const float* wf1 = (const float*)d_in[21];
    const float* bf1 = (const float*)d_in[22];
    const float* wf2 = (const float*)d_in[23];
    const float* bf2 = (const float*)d_in[24];

    // ws layout with lifetime aliasing:
    //  0..2   : idxP
    //  2..2.25: xxf
    //  4..12  : h1t
    //  12..20 : partF
    //  20..36 : f12 -> ZC (f12 dead after gemm13)
    char* ws = (char*)d_ws;
    int*   idxP  = (int*)ws;
    float* xxf   = (float*)(ws + (2u << 20));
    float* h1t   = (float*)(ws + (4u << 20));
    u64*   partF = (u64*)(ws + (12u << 20));
    float* f12   = (float*)(ws + (20u << 20));
    float* ZC    = (float*)(ws + (20u << 20));
    float* feat  = (float*)d_out;                 // [B*N][128]

    knn_point_kernel<<<dim3(NB * 128), dim3(256), 0, stream>>>(point, idxP);
    edge12_kernel<<<dim3(NB * NP / 4), dim3(256), 0, stream>>>(
        point, idxP, w11, b11, g11, bb11, w12, b12, g12, bb12, f12);
    gemm_act_kernel<128, 64, 1, true><<<dim3(NB * NP / 64), dim3(256), 0, stream>>>(
        f12, w13, b13, g13, bb13, h1t, xxf);
    knn_feat_kernel<<<dim3(NB * 32 * SPLIT), dim3(256), 0, stream>>>(h1t, xxf, partF);
    gemm_act_kernel<64, 128, 0, false><<<dim3(NB * NP / 64), dim3(256), 0, stream>>>(
        h1t, w15, b15, nullptr, nullptr, ZC, nullptr);
    edge5_gemm14_kernel<<<dim3(NB * NP / 64), dim3(256), 0, stream>>>(
        ZC, partF, g15, bb15, w14, b14, g14, bb14, feat);
    fc_head_kernel<<<dim3(NB * NP / 64), dim3(256), 0, stream>>>(
        feat, point, wf1, bf1, wf2, bf2, (float*)d_out);
}